// Round 1
// 731.961 us; speedup vs baseline: 1.3360x; 1.3360x over previous
//
#include <hip/hip_runtime.h>
#include <math.h>

// Problem constants (fixed by reference): B*S = 262144 rows
#define DQ 14      // query dim
#define HD 32      // hidden dim
#define DK 8       // projected dim
#define NK 240     // number of E8 root keys
#define DV 256     // value dim
#define RB 64      // rows per block
#define NFRAG 65536  // 16 nt * 8 ks * 64 lanes * 8 elems (padded K=256)

typedef __attribute__((ext_vector_type(8))) short bf16x8;  // 8 bf16 in 4 VGPRs
typedef __attribute__((ext_vector_type(4))) float f32x4;

__device__ __forceinline__ unsigned bf16_rn(float x) {
    unsigned u = __float_as_uint(x);
    return (u + 0x7fffu + ((u >> 16) & 1u)) >> 16;  // round-to-nearest-even
}

// ---- prep: values -> bf16 hi/lo B-fragments, fragment-major in workspace ----
// layout: [nt(16)][ks(8)][lane(64)][e(8)], element = values[k][n] with
//   n = nt*16 + (lane&15), k = ks*32 + (lane>>4)*8 + e, zero-padded for k>=240.
// Main kernel then loads each fragment as one fully-coalesced 1KiB dwordx4/wave.
__global__ void prep_values(const float* __restrict__ values,
                            unsigned short* __restrict__ ws_hi,
                            unsigned short* __restrict__ ws_lo) {
    int idx = blockIdx.x * 256 + threadIdx.x;
    int e  = idx & 7;
    int l  = (idx >> 3) & 63;
    int ks = (idx >> 9) & 7;
    int nt = idx >> 12;
    int k = ks * 32 + ((l >> 4) << 3) + e;
    int n = nt * 16 + (l & 15);
    float v = (k < NK) ? values[k * DV + n] : 0.0f;
    unsigned hb = bf16_rn(v);
    float hf = __uint_as_float(hb << 16);
    unsigned lb = bf16_rn(v - hf);           // v ~= hi + lo to ~2^-18 rel
    ws_hi[idx] = (unsigned short)hb;
    ws_lo[idx] = (unsigned short)lb;
}

// Fused: projection -> GELU -> projection -> L2norm -> sim -> softmax (fp32,
// identical math to previous version) -> content via bf16x3-split MFMA.
__global__ __launch_bounds__(256, 2)
void em_fused(const float* __restrict__ query,
              const float* __restrict__ W1, const float* __restrict__ b1,
              const float* __restrict__ W2, const float* __restrict__ b2,
              const float* __restrict__ keys,
              const unsigned short* __restrict__ ws_hi,
              const unsigned short* __restrict__ ws_lo,
              float* __restrict__ out_content, float* __restrict__ out_attn)
{
    __shared__ float s_x[RB][DQ];                       // 3584 B
    __shared__ float s_h[RB][HD + 1];                   // 8448 B
    __shared__ float s_q8[RB][DK + 1];                  // 2304 B
    __shared__ __align__(16) unsigned short s_Ah[RB * 256];  // 32768 B (swizzled)
    __shared__ __align__(16) unsigned short s_Al[RB * 256];  // 32768 B (swizzled)
    // total 79872 B -> 2 blocks/CU

    const int tid = threadIdx.x;
    const long row0 = (long)blockIdx.x * RB;

    // ---- stage x tile: 64 rows x 14, coalesced ----
    for (int e = tid; e < RB * DQ; e += 256) {
        s_x[e / DQ][e % DQ] = query[row0 * DQ + e];
    }
    __syncthreads();

    // ---- h = gelu(x @ W1^T + b1): 64 x 32 = 2048 tasks ----
    #pragma unroll
    for (int it = 0; it < (RB * HD) / 256; ++it) {
        int task = it * 256 + tid;
        int r = task >> 5, j = task & 31;
        float acc = b1[j];
        #pragma unroll
        for (int c = 0; c < DQ; ++c) acc += s_x[r][c] * W1[j * DQ + c];
        s_h[r][j] = 0.5f * acc * (1.0f + erff(acc * 0.70710678118654752f));
    }
    __syncthreads();

    // ---- q8 = h @ W2^T + b2: 64 x 8 = 512 tasks ----
    #pragma unroll
    for (int it = 0; it < (RB * DK) / 256; ++it) {
        int task = it * 256 + tid;
        int r = task >> 3, i = task & 7;
        float acc = b2[i];
        #pragma unroll
        for (int c = 0; c < HD; ++c) acc += s_h[r][c] * W2[i * HD + c];
        s_q8[r][i] = acc;
    }
    __syncthreads();

    // ---- L2 normalize q8 ----
    if (tid < RB) {
        float ss = 0.f;
        #pragma unroll
        for (int i = 0; i < DK; ++i) { float v = s_q8[tid][i]; ss += v * v; }
        float inv = 1.0f / fmaxf(sqrtf(ss), 1e-12f);
        #pragma unroll
        for (int i = 0; i < DK; ++i) s_q8[tid][i] *= inv;
    }
    __syncthreads();

    // ---- sim + softmax: wave handles 16 rows; lane owns t = 4*lane..4*lane+3 ----
    {
        const int wv = tid >> 6, lane = tid & 63;
        const int t0 = lane * 4;
        // hoist keys for this lane's 4 slots (reused across 16 rows)
        float kr[4][DK];
        #pragma unroll
        for (int s = 0; s < 4; ++s) {
            #pragma unroll
            for (int c = 0; c < DK; ++c)
                kr[s][c] = (t0 + s < NK) ? keys[(t0 + s) * DK + c] : 0.0f;
        }
        char* ahp = (char*)s_Ah;
        char* alp = (char*)s_Al;
        for (int rr = 0; rr < 16; ++rr) {
            const int r = wv * 16 + rr;
            float q[DK];
            #pragma unroll
            for (int c = 0; c < DK; ++c) q[c] = s_q8[r][c];
            float ex[4];
            float ssum = 0.f;
            #pragma unroll
            for (int s = 0; s < 4; ++s) {
                float sim = 0.f;
                #pragma unroll
                for (int c = 0; c < DK; ++c) sim += q[c] * kr[s][c];
                // BETA = 2.0; scores in [-2,2], no max-subtraction needed
                float v = (t0 + s < NK) ? __expf(2.0f * sim) : 0.0f;
                ex[s] = v;
                ssum += v;
            }
            #pragma unroll
            for (int m = 1; m < 64; m <<= 1) ssum += __shfl_xor(ssum, m, 64);
            const float inv = 1.0f / ssum;
            float a0 = ex[0] * inv, a1 = ex[1] * inv, a2 = ex[2] * inv, a3 = ex[3] * inv;
            if (t0 < NK) {  // lanes 60..63 are k-padding only
                *(float4*)&out_attn[(row0 + r) * NK + t0] =
                    make_float4(a0, a1, a2, a3);
            }
            // bf16 hi/lo split of attn row into swizzled A tiles (zero for pad)
            unsigned h0 = bf16_rn(a0), h1 = bf16_rn(a1), h2 = bf16_rn(a2), h3 = bf16_rn(a3);
            float f0 = __uint_as_float(h0 << 16), f1 = __uint_as_float(h1 << 16);
            float f2 = __uint_as_float(h2 << 16), f3 = __uint_as_float(h3 << 16);
            unsigned l0 = bf16_rn(a0 - f0), l1 = bf16_rn(a1 - f1);
            unsigned l2 = bf16_rn(a2 - f2), l3 = bf16_rn(a3 - f3);
            // row stride 512 B; XOR-swizzle bits 4..6 by (r&7) -> conflict-free frag reads
            unsigned off = ((unsigned)(r * 512 + lane * 8)) ^ (((unsigned)(r & 7)) << 4);
            *(ushort4*)(ahp + off) = make_ushort4((unsigned short)h0, (unsigned short)h1,
                                                  (unsigned short)h2, (unsigned short)h3);
            *(ushort4*)(alp + off) = make_ushort4((unsigned short)l0, (unsigned short)l1,
                                                  (unsigned short)l2, (unsigned short)l3);
        }
    }
    __syncthreads();

    // ---- content = attn @ values via MFMA, bf16x3 split (err ~2^-18 rel) ----
    // wave wv owns n-tiles wv*4..wv*4+3 and all 4 m-tiles; no barriers needed.
    {
        const int wv = tid >> 6, lane = tid & 63;
        const int l15 = lane & 15, l4 = lane >> 4;
        f32x4 acc[4][4];
        #pragma unroll
        for (int i = 0; i < 4; ++i)
            #pragma unroll
            for (int j = 0; j < 4; ++j)
                acc[i][j] = (f32x4){0.f, 0.f, 0.f, 0.f};

        const char* ahp = (const char*)s_Ah;
        const char* alp = (const char*)s_Al;
        const bf16x8* Bh = (const bf16x8*)ws_hi;
        const bf16x8* Bl = (const bf16x8*)ws_lo;

        #pragma unroll
        for (int ks = 0; ks < 8; ++ks) {
            bf16x8 bh[4], bl[4], ah[4], al[4];
            #pragma unroll
            for (int ntl = 0; ntl < 4; ++ntl) {
                int fi = (((wv * 4 + ntl) * 8 + ks) << 6) + lane;  // fragment-major
                bh[ntl] = Bh[fi];   // 1KiB coalesced, L2-resident
                bl[ntl] = Bl[fi];
            }
            #pragma unroll
            for (int mt = 0; mt < 4; ++mt) {
                int m = mt * 16 + l15;
                unsigned off = ((unsigned)(m * 512 + ks * 64 + l4 * 16)) ^
                               (((unsigned)(m & 7)) << 4);
                ah[mt] = *(const bf16x8*)(ahp + off);
                al[mt] = *(const bf16x8*)(alp + off);
            }
            #pragma unroll
            for (int ntl = 0; ntl < 4; ++ntl) {
                #pragma unroll
                for (int mt = 0; mt < 4; ++mt) {
                    acc[mt][ntl] = __builtin_amdgcn_mfma_f32_16x16x32_bf16(
                        ah[mt], bh[ntl], acc[mt][ntl], 0, 0, 0);
                    acc[mt][ntl] = __builtin_amdgcn_mfma_f32_16x16x32_bf16(
                        al[mt], bh[ntl], acc[mt][ntl], 0, 0, 0);
                    acc[mt][ntl] = __builtin_amdgcn_mfma_f32_16x16x32_bf16(
                        ah[mt], bl[ntl], acc[mt][ntl], 0, 0, 0);
                }
            }
        }

        // C/D layout (m89-verified): col = lane&15, row = (lane>>4)*4 + reg
        #pragma unroll
        for (int mt = 0; mt < 4; ++mt) {
            #pragma unroll
            for (int ntl = 0; ntl < 4; ++ntl) {
                const int n = (wv * 4 + ntl) * 16 + l15;
                #pragma unroll
                for (int j = 0; j < 4; ++j) {
                    long row = row0 + mt * 16 + l4 * 4 + j;
                    out_content[row * DV + n] = acc[mt][ntl][j];
                }
            }
        }
    }
}

extern "C" void kernel_launch(void* const* d_in, const int* in_sizes, int n_in,
                              void* d_out, int out_size, void* d_ws, size_t ws_size,
                              hipStream_t stream) {
    const float* query  = (const float*)d_in[0];
    const float* W1     = (const float*)d_in[1];
    const float* b1     = (const float*)d_in[2];
    const float* W2     = (const float*)d_in[3];
    const float* b2     = (const float*)d_in[4];
    const float* values = (const float*)d_in[5];
    const float* keys   = (const float*)d_in[6];

    const int nrows = in_sizes[0] / DQ;            // 262144
    float* out_content = (float*)d_out;            // [nrows, 256]
    float* out_attn    = out_content + (size_t)nrows * DV;  // [nrows, 240]

    // workspace: 2 x 128 KiB bf16 fragment tables (requires ws_size >= 256 KiB)
    unsigned short* wh = (unsigned short*)d_ws;
    unsigned short* wl = wh + NFRAG;

    prep_values<<<NFRAG / 256, 256, 0, stream>>>(values, wh, wl);
    em_fused<<<nrows / RB, 256, 0, stream>>>(query, W1, b1, W2, b2, keys,
                                             wh, wl, out_content, out_attn);
}

// Round 2
// 697.949 us; speedup vs baseline: 1.4011x; 1.0487x over previous
//
#include <hip/hip_runtime.h>
#include <math.h>

// Problem constants (fixed by reference): B*S = 262144 rows
#define DQ 14      // query dim
#define HD 32      // hidden dim
#define DK 8       // projected dim
#define NK 240     // number of E8 root keys
#define DV 256     // value dim
#define RB 64      // rows per block
#define NT 512     // threads per block (8 waves)
#define NFRAG 65536  // 16 nt * 8 ks * 64 lanes * 8 elems (padded K=256)

typedef __attribute__((ext_vector_type(8))) short bf16x8;  // 8 bf16 in 4 VGPRs
typedef __attribute__((ext_vector_type(4))) float f32x4;

__device__ __forceinline__ unsigned bf16_rn(float x) {
    unsigned u = __float_as_uint(x);
    return (u + 0x7fffu + ((u >> 16) & 1u)) >> 16;  // round-to-nearest-even
}

// ---- prep: values -> bf16 hi/lo fragments, fragment-major in workspace ----
// layout: [nt(16)][ks(8)][lane(64)][e(8)], element = values[k][n] with
//   n = nt*16 + (lane&15), k = ks*32 + (lane>>4)*8 + e, zero-padded for k>=240.
// This is simultaneously the A-operand layout for the transposed-output MFMA:
//   A[i=n][k] = V[k][n] with i = lane&15, k-slice = lane>>4.
__global__ void prep_values(const float* __restrict__ values,
                            unsigned short* __restrict__ ws_hi,
                            unsigned short* __restrict__ ws_lo) {
    int idx = blockIdx.x * 256 + threadIdx.x;
    int e  = idx & 7;
    int l  = (idx >> 3) & 63;
    int ks = (idx >> 9) & 7;
    int nt = idx >> 12;
    int k = ks * 32 + ((l >> 4) << 3) + e;
    int n = nt * 16 + (l & 15);
    float v = (k < NK) ? values[k * DV + n] : 0.0f;
    unsigned hb = bf16_rn(v);
    float hf = __uint_as_float(hb << 16);
    unsigned lb = bf16_rn(v - hf);           // v ~= hi + lo to ~2^-18 rel
    ws_hi[idx] = (unsigned short)hb;
    ws_lo[idx] = (unsigned short)lb;
}

// Fused: projection -> GELU -> projection -> L2norm -> sim -> softmax (fp32)
// -> content via bf16x3-split MFMA with transposed output (float4 C-stores).
// 512 threads, LDS 79872 B -> 2 blocks/CU = 16 waves/CU.
__global__ __launch_bounds__(NT, 4)
void em_fused(const float* __restrict__ query,
              const float* __restrict__ W1, const float* __restrict__ b1,
              const float* __restrict__ W2, const float* __restrict__ b2,
              const float* __restrict__ keys,
              const unsigned short* __restrict__ ws_hi,
              const unsigned short* __restrict__ ws_lo,
              float* __restrict__ out_content, float* __restrict__ out_attn)
{
    __shared__ float s_x[RB][DQ];                       // 3584 B
    __shared__ float s_h[RB][HD + 1];                   // 8448 B
    __shared__ float s_q8[RB][DK + 1];                  // 2304 B
    __shared__ __align__(16) unsigned short s_Ah[RB * 256];  // 32768 B (swizzled)
    __shared__ __align__(16) unsigned short s_Al[RB * 256];  // 32768 B (swizzled)
    // total 79872 B -> 2 blocks/CU -> 16 waves/CU

    const int tid = threadIdx.x;
    const long row0 = (long)blockIdx.x * RB;

    // ---- stage x tile: 64 rows x 14, coalesced ----
    for (int e = tid; e < RB * DQ; e += NT) {
        s_x[e / DQ][e % DQ] = query[row0 * DQ + e];
    }
    __syncthreads();

    // ---- h = gelu(x @ W1^T + b1): 64 x 32 = 2048 tasks ----
    #pragma unroll
    for (int it = 0; it < (RB * HD) / NT; ++it) {
        int task = it * NT + tid;
        int r = task >> 5, j = task & 31;
        float acc = b1[j];
        #pragma unroll
        for (int c = 0; c < DQ; ++c) acc += s_x[r][c] * W1[j * DQ + c];
        s_h[r][j] = 0.5f * acc * (1.0f + erff(acc * 0.70710678118654752f));
    }
    __syncthreads();

    // ---- q8 = h @ W2^T + b2: 64 x 8 = 512 tasks (exactly one per thread) ----
    {
        int r = tid >> 3, i = tid & 7;
        float acc = b2[i];
        #pragma unroll
        for (int c = 0; c < HD; ++c) acc += s_h[r][c] * W2[i * HD + c];
        s_q8[r][i] = acc;
    }
    __syncthreads();

    // ---- L2 normalize q8 ----
    if (tid < RB) {
        float ss = 0.f;
        #pragma unroll
        for (int i = 0; i < DK; ++i) { float v = s_q8[tid][i]; ss += v * v; }
        float inv = 1.0f / fmaxf(sqrtf(ss), 1e-12f);
        #pragma unroll
        for (int i = 0; i < DK; ++i) s_q8[tid][i] *= inv;
    }
    __syncthreads();

    // ---- sim + softmax: each wave handles 8 rows; lane owns t = 4*lane..4*lane+3
    {
        const int wv = tid >> 6, lane = tid & 63;
        const int t0 = lane * 4;
        // hoist keys for this lane's 4 slots (reused across 8 rows)
        float kr[4][DK];
        #pragma unroll
        for (int s = 0; s < 4; ++s) {
            #pragma unroll
            for (int c = 0; c < DK; ++c)
                kr[s][c] = (t0 + s < NK) ? keys[(t0 + s) * DK + c] : 0.0f;
        }
        char* ahp = (char*)s_Ah;
        char* alp = (char*)s_Al;
        for (int rr = 0; rr < 8; ++rr) {
            const int r = wv * 8 + rr;
            float q[DK];
            #pragma unroll
            for (int c = 0; c < DK; ++c) q[c] = s_q8[r][c];
            float ex[4];
            float ssum = 0.f;
            #pragma unroll
            for (int s = 0; s < 4; ++s) {
                float sim = 0.f;
                #pragma unroll
                for (int c = 0; c < DK; ++c) sim += q[c] * kr[s][c];
                // BETA = 2.0; scores in [-2,2], no max-subtraction needed
                float v = (t0 + s < NK) ? __expf(2.0f * sim) : 0.0f;
                ex[s] = v;
                ssum += v;
            }
            #pragma unroll
            for (int m = 1; m < 64; m <<= 1) ssum += __shfl_xor(ssum, m, 64);
            const float inv = 1.0f / ssum;
            float a0 = ex[0] * inv, a1 = ex[1] * inv, a2 = ex[2] * inv, a3 = ex[3] * inv;
            if (t0 < NK) {  // lanes 60..63 are k-padding only
                *(float4*)&out_attn[(row0 + r) * NK + t0] =
                    make_float4(a0, a1, a2, a3);
            }
            // bf16 hi/lo split of attn row into swizzled B tiles (zero for pad)
            unsigned h0 = bf16_rn(a0), h1 = bf16_rn(a1), h2 = bf16_rn(a2), h3 = bf16_rn(a3);
            float f0 = __uint_as_float(h0 << 16), f1 = __uint_as_float(h1 << 16);
            float f2 = __uint_as_float(h2 << 16), f3 = __uint_as_float(h3 << 16);
            unsigned l0 = bf16_rn(a0 - f0), l1 = bf16_rn(a1 - f1);
            unsigned l2 = bf16_rn(a2 - f2), l3 = bf16_rn(a3 - f3);
            // row stride 512 B; XOR-swizzle bits 4..6 by (r&7) -> balanced frag reads
            unsigned off = ((unsigned)(r * 512 + lane * 8)) ^ (((unsigned)(r & 7)) << 4);
            *(ushort4*)(ahp + off) = make_ushort4((unsigned short)h0, (unsigned short)h1,
                                                  (unsigned short)h2, (unsigned short)h3);
            *(ushort4*)(alp + off) = make_ushort4((unsigned short)l0, (unsigned short)l1,
                                                  (unsigned short)l2, (unsigned short)l3);
        }
    }
    __syncthreads();

    // ---- content^T via MFMA: D[n][m] = sum_k V[k][n] * attn[m][k] ----
    // A operand = values fragments (global ws, L2-resident), B = attn (LDS).
    // C/D mapping: col = lane&15 -> m_local, row = (lane>>4)*4+reg -> n_local,
    // so each lane's 4 regs are 4 CONSECUTIVE n -> float4 store.
    // Wave wv owns n-tiles wv*2, wv*2+1 and all 4 m-tiles; no barriers needed.
    {
        const int wv = tid >> 6, lane = tid & 63;
        const int l15 = lane & 15, l4 = lane >> 4;
        f32x4 acc[4][2];
        #pragma unroll
        for (int i = 0; i < 4; ++i)
            #pragma unroll
            for (int j = 0; j < 2; ++j)
                acc[i][j] = (f32x4){0.f, 0.f, 0.f, 0.f};

        const char* ahp = (const char*)s_Ah;
        const char* alp = (const char*)s_Al;
        const bf16x8* Vh = (const bf16x8*)ws_hi;
        const bf16x8* Vl = (const bf16x8*)ws_lo;

        #pragma unroll
        for (int ks = 0; ks < 8; ++ks) {
            bf16x8 vh[2], vl[2], ah[4], al[4];
            #pragma unroll
            for (int ntl = 0; ntl < 2; ++ntl) {
                int fi = (((wv * 2 + ntl) * 8 + ks) << 6) + lane;  // fragment-major
                vh[ntl] = Vh[fi];   // 1KiB coalesced, L2-resident
                vl[ntl] = Vl[fi];
            }
            #pragma unroll
            for (int mt = 0; mt < 4; ++mt) {
                int m = mt * 16 + l15;
                unsigned off = ((unsigned)(m * 512 + ks * 64 + l4 * 16)) ^
                               (((unsigned)(m & 7)) << 4);
                ah[mt] = *(const bf16x8*)(ahp + off);
                al[mt] = *(const bf16x8*)(alp + off);
            }
            #pragma unroll
            for (int ntl = 0; ntl < 2; ++ntl) {
                #pragma unroll
                for (int mt = 0; mt < 4; ++mt) {
                    // full = (vh+vl)*(ah+al) ~= vh*ah + vl*ah + vh*al
                    acc[mt][ntl] = __builtin_amdgcn_mfma_f32_16x16x32_bf16(
                        vh[ntl], ah[mt], acc[mt][ntl], 0, 0, 0);
                    acc[mt][ntl] = __builtin_amdgcn_mfma_f32_16x16x32_bf16(
                        vl[ntl], ah[mt], acc[mt][ntl], 0, 0, 0);
                    acc[mt][ntl] = __builtin_amdgcn_mfma_f32_16x16x32_bf16(
                        vh[ntl], al[mt], acc[mt][ntl], 0, 0, 0);
                }
            }
        }

        // store: lane (l15 -> m), regs -> 4 consecutive n: one float4 per tile
        #pragma unroll
        for (int mt = 0; mt < 4; ++mt) {
            const long row = row0 + mt * 16 + l15;
            #pragma unroll
            for (int ntl = 0; ntl < 2; ++ntl) {
                const int n = (wv * 2 + ntl) * 16 + l4 * 4;
                float4 o = make_float4(acc[mt][ntl][0], acc[mt][ntl][1],
                                       acc[mt][ntl][2], acc[mt][ntl][3]);
                *(float4*)&out_content[row * DV + n] = o;
            }
        }
    }
}

extern "C" void kernel_launch(void* const* d_in, const int* in_sizes, int n_in,
                              void* d_out, int out_size, void* d_ws, size_t ws_size,
                              hipStream_t stream) {
    const float* query  = (const float*)d_in[0];
    const float* W1     = (const float*)d_in[1];
    const float* b1     = (const float*)d_in[2];
    const float* W2     = (const float*)d_in[3];
    const float* b2     = (const float*)d_in[4];
    const float* values = (const float*)d_in[5];
    const float* keys   = (const float*)d_in[6];

    const int nrows = in_sizes[0] / DQ;            // 262144
    float* out_content = (float*)d_out;            // [nrows, 256]
    float* out_attn    = out_content + (size_t)nrows * DV;  // [nrows, 240]

    // workspace: 2 x 128 KiB bf16 fragment tables (requires ws_size >= 256 KiB)
    unsigned short* wh = (unsigned short*)d_ws;
    unsigned short* wl = wh + NFRAG;

    prep_values<<<NFRAG / 256, 256, 0, stream>>>(values, wh, wl);
    em_fused<<<nrows / RB, NT, 0, stream>>>(query, W1, b1, W2, b2, keys,
                                            wh, wl, out_content, out_attn);
}